// Round 12
// baseline (491.598 us; speedup 1.0000x reference)
//
#include <hip/hip_runtime.h>

#define H 128
#define EPSILON 0.7071067811865476f
#define NEPS 1e-8f

typedef short bf16x8 __attribute__((ext_vector_type(8)));
typedef float f32x4 __attribute__((ext_vector_type(4)));
typedef unsigned short ushort_t;

__device__ __forceinline__ float silu_f(float x) {
    return x / (1.0f + __expf(-x));
}
__device__ __forceinline__ unsigned short bfround(float w) {
    unsigned ub = __float_as_uint(w);
    return (unsigned short)((ub + 0x7FFF + ((ub >> 16) & 1)) >> 16);
}
__device__ __forceinline__ float bfu(unsigned short u) { return __uint_as_float(((unsigned)u) << 16); }

// pack one element of a K x N weight into fragment-major bf16
// elem (ks, ct, lane, j) at ((ks*CT+ct)*64+lane)*8+j = W[ks*32+(lane>>4)*8+j][ct*16+(lane&15)]
__device__ __forceinline__ void pack_one(const float* __restrict__ W, int N,
                                         ushort_t* __restrict__ p, int tid) {
    int CT = N >> 4;
    int j = tid & 7;
    int l = (tid >> 3) & 63;
    int rest = tid >> 9;
    int ct = rest % CT;
    int ks = rest / CT;
    int row = ks * 32 + ((l >> 4) << 3) + j;
    int col = ct * 16 + (l & 15);
    p[tid] = bfround(W[(size_t)row * N + col]);
}

// ---------------- K_prep: pack 5 weights + edge histogram (cnt pre-zeroed by memset) ----------------
__global__ void k_prep(const float* __restrict__ Wi1, const float* __restrict__ Wi2,
                       const float* __restrict__ Wvm, const float* __restrict__ Wm1,
                       const float* __restrict__ Wm2,
                       ushort_t* __restrict__ Wi1p, ushort_t* __restrict__ Wi2p,
                       ushort_t* __restrict__ Wvp, ushort_t* __restrict__ Wm1p,
                       ushort_t* __restrict__ Wm2p,
                       const int* __restrict__ senders, int* __restrict__ cnt, int n_edges) {
    int gid = blockIdx.x * blockDim.x + threadIdx.x;
    int stride = gridDim.x * blockDim.x;
    int S1 = 16384;
    int S2 = S1 + 49152;
    int S3 = S2 + 32768;
    int S4 = S3 + 32768;
    int S5 = S4 + 49152;
    int S6 = S5 + n_edges;
    for (int i = gid; i < S6; i += stride) {
        if (i < S1)      pack_one(Wi1, 128, Wi1p, i);
        else if (i < S2) pack_one(Wi2, 384, Wi2p, i - S1);
        else if (i < S3) pack_one(Wvm, 256, Wvp,  i - S2);
        else if (i < S4) pack_one(Wm1, 128, Wm1p, i - S3);
        else if (i < S5) pack_one(Wm2, 384, Wm2p, i - S4);
        else             atomicAdd(&cnt[senders[i - S5]], 1);
    }
}

// ---------------- K1 (MFMA): x = silu(s@Wi1+bi1)@Wi2+bi2 -> xv[0:384]; also v -> xv[384:768] ----------------
__global__ __launch_bounds__(256, 6) void k1_mfma(
        const float* __restrict__ s, const float4* __restrict__ v4,
        const ushort_t* __restrict__ W1p, const ushort_t* __restrict__ W2p,
        const float* __restrict__ bi1, const float* __restrict__ bi2,
        ushort_t* __restrict__ xv, int n_nodes) {
    __shared__ ushort_t Ab[16 * 136];
    __shared__ ushort_t Hb[16 * 136];
    int t = threadIdx.x;
    int node0 = blockIdx.x * 16;
    int wv = t >> 6, lane = t & 63;
    int g = lane >> 4, cl = lane & 15;

    #pragma unroll
    for (int i = 0; i < 8; ++i) {
        int flat = t + i * 256;
        int n = flat >> 7, k = flat & 127;
        int node = node0 + n; if (node >= n_nodes) node = n_nodes - 1;
        Ab[n * 136 + k] = bfround(s[(size_t)node * 128 + k]);
    }
    __syncthreads();

    f32x4 acc1[2] = {};
    #pragma unroll
    for (int ks = 0; ks < 4; ++ks) {
        bf16x8 ah = *(const bf16x8*)&Ab[cl * 136 + ks * 32 + g * 8];
        #pragma unroll
        for (int c = 0; c < 2; ++c) {
            int ct = wv * 2 + c;
            bf16x8 bh = *(const bf16x8*)&W1p[((size_t)(ks * 8 + ct) * 64 + lane) * 8];
            acc1[c] = __builtin_amdgcn_mfma_f32_16x16x32_bf16(ah, bh, acc1[c], 0, 0, 0);
        }
    }
    #pragma unroll
    for (int c = 0; c < 2; ++c) {
        int col = (wv * 2 + c) * 16 + cl;
        float bias = bi1[col];
        #pragma unroll
        for (int r = 0; r < 4; ++r) {
            int row = g * 4 + r;
            Hb[row * 136 + col] = bfround(silu_f(acc1[c][r] + bias));
        }
    }
    __syncthreads();

    f32x4 acc2[6] = {};
    #pragma unroll
    for (int ks = 0; ks < 4; ++ks) {
        bf16x8 ah = *(const bf16x8*)&Hb[cl * 136 + ks * 32 + g * 8];
        #pragma unroll
        for (int c = 0; c < 6; ++c) {
            int ct = wv * 6 + c;
            bf16x8 bh = *(const bf16x8*)&W2p[((size_t)(ks * 24 + ct) * 64 + lane) * 8];
            acc2[c] = __builtin_amdgcn_mfma_f32_16x16x32_bf16(ah, bh, acc2[c], 0, 0, 0);
        }
    }
    #pragma unroll
    for (int c = 0; c < 6; ++c) {
        int col = (wv * 6 + c) * 16 + cl;
        float bias = bi2[col];
        #pragma unroll
        for (int r = 0; r < 4; ++r) {
            int node = node0 + g * 4 + r;
            if (node < n_nodes) xv[(size_t)node * 768 + col] = bfround(acc2[c][r] + bias);
        }
    }

    // convert these 16 nodes' v rows -> xv[384:768]
    #pragma unroll
    for (int i = 0; i < 6; ++i) {
        int flat = t + i * 256;               // 0..1535 = 16 nodes * 96 float4
        int n = flat / 96, part = flat - n * 96;
        int node = node0 + n;
        if (node < n_nodes) {
            float4 f = v4[(size_t)node * 96 + part];
            ushort4 u;
            u.x = bfround(f.x); u.y = bfround(f.y); u.z = bfround(f.z); u.w = bfround(f.w);
            *(ushort4*)&xv[(size_t)node * 768 + 384 + 4 * part] = u;
        }
    }
}

// ---------------- CSR build ----------------
__global__ void k_alloc(const int* __restrict__ cnt, int* __restrict__ starts,
                        int* __restrict__ head, int* __restrict__ cursor, int n) {
    int i = blockIdx.x * blockDim.x + threadIdx.x;
    int lane = threadIdx.x & 63;
    int c = (i < n) ? cnt[i] : 0;
    int pref = c;
    #pragma unroll
    for (int off = 1; off < 64; off <<= 1) {
        int up = __shfl_up(pref, off, 64);
        if (lane >= off) pref += up;
    }
    int total = __shfl(pref, 63, 64);
    int base = 0;
    if (lane == 63) base = atomicAdd(cursor, total);
    base = __shfl(base, 63, 64);
    if (i < n) { int p = base + pref - c; starts[i] = p; head[i] = p; }
}

__global__ void k_scatter(const int* __restrict__ senders, const int* __restrict__ receivers,
                          const float* __restrict__ dir, int* __restrict__ head,
                          int* __restrict__ eord, float4* __restrict__ edir, int n_edges) {
    int e = blockIdx.x * blockDim.x + threadIdx.x;
    if (e < n_edges) {
        int p = atomicAdd(&head[senders[e]], 1);
        eord[p] = e;
        float4 ed;
        ed.x = dir[3 * (size_t)e + 0];
        ed.y = dir[3 * (size_t)e + 1];
        ed.z = dir[3 * (size_t)e + 2];
        ed.w = __int_as_float(receivers[e]);
        edir[p] = ed;
    }
}

// ---------------- K2 (CSR): 512 threads, 16 edge slots -> one-burst edge parallelism ----------------
__global__ __launch_bounds__(512) void k2_csr(
        const float4* __restrict__ s4, const ushort_t* __restrict__ xv,
        const float* __restrict__ wf, const int* __restrict__ starts,
        const int* __restrict__ cnt, const int* __restrict__ eord,
        const float4* __restrict__ edir, ushort_t* __restrict__ mid, int n_nodes) {
    __shared__ float4 red[16][128];
    int node = blockIdx.x;
    int t = threadIdx.x;
    int slot = t >> 5, lane = t & 31;
    int beg = starts[node], num = cnt[node];
    float4 ds  = {0.f, 0.f, 0.f, 0.f};
    float4 dv0 = {0.f, 0.f, 0.f, 0.f};
    float4 dv1 = {0.f, 0.f, 0.f, 0.f};
    float4 dv2 = {0.f, 0.f, 0.f, 0.f};
    for (int q = slot; q < num; q += 16) {
        int e = eord[beg + q];
        float4 ed = edir[beg + q];
        int r = __float_as_int(ed.w);
        const f32x4*    we  = (const f32x4*)(wf + (size_t)e * 384);
        const ushort_t* xvr = xv + (size_t)r * 768;
        // non-temporal: Wij is a 922 MB read-once stream; don't evict xv from L2/L3
        f32x4 wa = __builtin_nontemporal_load(we + lane);
        f32x4 wb = __builtin_nontemporal_load(we + 32 + lane);
        f32x4 wc = __builtin_nontemporal_load(we + 64 + lane);
        ushort4 xa = *(const ushort4*)&xvr[4 * lane];
        ushort4 xb = *(const ushort4*)&xvr[128 + 4 * lane];
        ushort4 xc = *(const ushort4*)&xvr[256 + 4 * lane];
        ushort4 va = *(const ushort4*)&xvr[384 + 4 * lane];
        ushort4 vb = *(const ushort4*)&xvr[512 + 4 * lane];
        ushort4 vc = *(const ushort4*)&xvr[640 + 4 * lane];
        float bx = wb[0] * bfu(xb.x), by = wb[1] * bfu(xb.y), bz = wb[2] * bfu(xb.z), bw = wb[3] * bfu(xb.w);
        float cx = wc[0] * bfu(xc.x), cy = wc[1] * bfu(xc.y), cz = wc[2] * bfu(xc.z), cw = wc[3] * bfu(xc.w);
        ds.x += wa[0] * bfu(xa.x); ds.y += wa[1] * bfu(xa.y);
        ds.z += wa[2] * bfu(xa.z); ds.w += wa[3] * bfu(xa.w);
        dv0.x += bx * ed.x + cx * bfu(va.x); dv0.y += by * ed.x + cy * bfu(va.y);
        dv0.z += bz * ed.x + cz * bfu(va.z); dv0.w += bw * ed.x + cw * bfu(va.w);
        dv1.x += bx * ed.y + cx * bfu(vb.x); dv1.y += by * ed.y + cy * bfu(vb.y);
        dv1.z += bz * ed.y + cz * bfu(vb.z); dv1.w += bw * ed.y + cw * bfu(vb.w);
        dv2.x += bx * ed.z + cx * bfu(vc.x); dv2.y += by * ed.z + cy * bfu(vc.y);
        dv2.z += bz * ed.z + cz * bfu(vc.z); dv2.w += bw * ed.z + cw * bfu(vc.w);
    }
    red[slot][lane]      = ds;
    red[slot][32 + lane] = dv0;
    red[slot][64 + lane] = dv1;
    red[slot][96 + lane] = dv2;
    __syncthreads();
    if (t < 128) {
        float4 acc = red[0][t];
        #pragma unroll
        for (int q2 = 1; q2 < 16; ++q2) {
            float4 r2 = red[q2][t];
            acc.x += r2.x; acc.y += r2.y; acc.z += r2.z; acc.w += r2.w;
        }
        int which = t >> 5, hh = t & 31;
        float4 base;
        if (which == 0) {
            base = s4[(size_t)node * 32 + hh];
        } else {
            ushort4 u = *(const ushort4*)&xv[(size_t)node * 768 + 384 + (size_t)(which - 1) * 128 + 4 * hh];
            base.x = bfu(u.x); base.y = bfu(u.y); base.z = bfu(u.z); base.w = bfu(u.w);
        }
        ushort4 o;
        o.x = bfround((base.x + acc.x) * EPSILON);
        o.y = bfround((base.y + acc.y) * EPSILON);
        o.z = bfround((base.z + acc.z) * EPSILON);
        o.w = bfround((base.w + acc.w) * EPSILON);
        *(ushort4*)&mid[(size_t)node * 512 + 4 * t] = o;
    }
}

// ---------------- K3 (MFMA): fused update; reads bf16 mid, writes fp32 out ----------------
__global__ __launch_bounds__(256, 3) void k3_mfma(
        const ushort_t* __restrict__ mid,
        const ushort_t* __restrict__ Wvp, const ushort_t* __restrict__ W1p,
        const ushort_t* __restrict__ W2p,
        const float* __restrict__ bm1, const float* __restrict__ bm2,
        float* __restrict__ out, int n_nodes) {
    __shared__ __align__(16) char pool[51968];
    ushort_t* Ab  = (ushort_t*)pool;
    ushort_t* vlb = (ushort_t*)(pool + 13056);
    ushort_t* vrc = (ushort_t*)(pool + 26112);
    ushort_t* Tb  = (ushort_t*)(pool + 39168);
    ushort_t* Hb  = (ushort_t*)(pool + 47616);
    float* C3 = (float*)(pool + 26112);   // [16][400]

    int t = threadIdx.x;
    int node0 = blockIdx.x * 16;
    int wv = t >> 6, lane = t & 63;
    int g = lane >> 4, cl = lane & 15;

    float smid_reg[8], dot_reg[8];

    #pragma unroll
    for (int i = 0; i < 6; ++i) {
        int flat4 = t + i * 256;
        int row = flat4 >> 5, k4 = flat4 & 31;
        int n = row / 3, d = row - n * 3;
        int node = node0 + n; if (node >= n_nodes) node = n_nodes - 1;
        ushort4 u = *(const ushort4*)&mid[(size_t)node * 512 + (size_t)(1 + d) * 128 + 4 * k4];
        *(ushort4*)&Ab[row * 136 + 4 * k4] = u;
    }
    #pragma unroll
    for (int i = 0; i < 8; ++i) {
        int flat = t + i * 256;
        int n = flat >> 7, k = flat & 127;
        int node = node0 + n; if (node >= n_nodes) node = n_nodes - 1;
        smid_reg[i] = bfu(mid[(size_t)node * 512 + k]);
    }
    __syncthreads();

    // GEMM1: (48x128)@(128x256) -> v_l | v_r
    #pragma unroll
    for (int rt = 0; rt < 3; ++rt) {
        bf16x8 ah[4];
        #pragma unroll
        for (int ks = 0; ks < 4; ++ks)
            ah[ks] = *(const bf16x8*)&Ab[(rt * 16 + cl) * 136 + ks * 32 + g * 8];
        f32x4 acc[4] = {};
        #pragma unroll
        for (int ks = 0; ks < 4; ++ks) {
            #pragma unroll
            for (int c = 0; c < 4; ++c) {
                int ct = wv * 4 + c;
                bf16x8 bh = *(const bf16x8*)&Wvp[((size_t)(ks * 16 + ct) * 64 + lane) * 8];
                acc[c] = __builtin_amdgcn_mfma_f32_16x16x32_bf16(ah[ks], bh, acc[c], 0, 0, 0);
            }
        }
        #pragma unroll
        for (int c = 0; c < 4; ++c) {
            int col = (wv * 4 + c) * 16 + cl;
            ushort_t* dst = (col < 128) ? vlb : vrc;
            int cc = col & 127;
            #pragma unroll
            for (int r = 0; r < 4; ++r)
                dst[(rt * 16 + g * 4 + r) * 136 + cc] = bfround(acc[c][r]);
        }
    }
    __syncthreads();

    // phase 2: v_norm, dot -> regs; build ts
    #pragma unroll
    for (int i = 0; i < 8; ++i) {
        int flat = t + i * 256;
        int n = flat >> 7, h = flat & 127;
        float r0 = bfu(vrc[(3 * n + 0) * 136 + h]);
        float r1 = bfu(vrc[(3 * n + 1) * 136 + h]);
        float r2 = bfu(vrc[(3 * n + 2) * 136 + h]);
        float l0 = bfu(vlb[(3 * n + 0) * 136 + h]);
        float l1 = bfu(vlb[(3 * n + 1) * 136 + h]);
        float l2 = bfu(vlb[(3 * n + 2) * 136 + h]);
        float nrm = sqrtf(r0 * r0 + r1 * r1 + r2 * r2 + NEPS);
        dot_reg[i] = r0 * l0 + r1 * l1 + r2 * l2;
        Tb[n * 264 + 128 + h] = bfround(nrm);
        Tb[n * 264 + h] = bfround(smid_reg[i]);
    }
    __syncthreads();

    // GEMM2: (16x256)@(256x128) + bm1 -> silu -> h1
    f32x4 acc2[2] = {};
    #pragma unroll
    for (int ks = 0; ks < 8; ++ks) {
        bf16x8 ah = *(const bf16x8*)&Tb[cl * 264 + ks * 32 + g * 8];
        #pragma unroll
        for (int c = 0; c < 2; ++c) {
            int ct = wv * 2 + c;
            bf16x8 bh = *(const bf16x8*)&W1p[((size_t)(ks * 8 + ct) * 64 + lane) * 8];
            acc2[c] = __builtin_amdgcn_mfma_f32_16x16x32_bf16(ah, bh, acc2[c], 0, 0, 0);
        }
    }
    #pragma unroll
    for (int c = 0; c < 2; ++c) {
        int col = (wv * 2 + c) * 16 + cl;
        float bias = bm1[col];
        #pragma unroll
        for (int r = 0; r < 4; ++r) {
            int row = g * 4 + r;
            Hb[row * 136 + col] = bfround(silu_f(acc2[c][r] + bias));
        }
    }
    __syncthreads();

    // GEMM3: (16x128)@(128x384) + bm2 -> C3 (overlay)
    f32x4 acc3[6] = {};
    #pragma unroll
    for (int ks = 0; ks < 4; ++ks) {
        bf16x8 ah = *(const bf16x8*)&Hb[cl * 136 + ks * 32 + g * 8];
        #pragma unroll
        for (int c = 0; c < 6; ++c) {
            int ct = wv * 6 + c;
            bf16x8 bh = *(const bf16x8*)&W2p[((size_t)(ks * 24 + ct) * 64 + lane) * 8];
            acc3[c] = __builtin_amdgcn_mfma_f32_16x16x32_bf16(ah, bh, acc3[c], 0, 0, 0);
        }
    }
    __syncthreads();
    #pragma unroll
    for (int c = 0; c < 6; ++c) {
        int col = (wv * 6 + c) * 16 + cl;
        float bias = bm2[col];
        #pragma unroll
        for (int r = 0; r < 4; ++r)
            C3[(g * 4 + r) * 400 + col] = acc3[c][r] + bias;
    }
    __syncthreads();

    // final combine (non-temporal stores: out is write-once)
    #pragma unroll
    for (int i = 0; i < 8; ++i) {
        int flat = t + i * 256;
        int n = flat >> 7, h = flat & 127;
        int node = node0 + n;
        if (node >= n_nodes) continue;
        float ds_u = C3[n * 400 + h];
        float dv_u = C3[n * 400 + 128 + h];
        float dsv  = C3[n * 400 + 256 + h] * dot_reg[i];
        __builtin_nontemporal_store((smid_reg[i] + ds_u + dsv) * EPSILON,
                                    &out[(size_t)node * 512 + h]);
        #pragma unroll
        for (int d = 0; d < 3; ++d) {
            int row = 3 * n + d;
            float vmid = bfu(Ab[row * 136 + h]);
            float vl_v = bfu(vlb[row * 136 + h]);
            __builtin_nontemporal_store((vmid + vl_v * dv_u) * EPSILON,
                                        &out[(size_t)node * 512 + 128 + d * 128 + h]);
        }
    }
}

static inline size_t align_up(size_t x, size_t a) { return (x + a - 1) / a * a; }

extern "C" void kernel_launch(void* const* d_in, const int* in_sizes, int n_in,
                              void* d_out, int out_size, void* d_ws, size_t ws_size,
                              hipStream_t stream) {
    const float* s       = (const float*)d_in[0];
    const float* v       = (const float*)d_in[1];
    const float* dir     = (const float*)d_in[2];
    const float* Wij     = (const float*)d_in[3];
    const int*   senders = (const int*)d_in[4];
    const int*   recv    = (const int*)d_in[5];
    const float* Wi1     = (const float*)d_in[6];
    const float* bi1     = (const float*)d_in[7];
    const float* Wi2     = (const float*)d_in[8];
    const float* bi2     = (const float*)d_in[9];
    const float* Wm1     = (const float*)d_in[10];
    const float* bm1     = (const float*)d_in[11];
    const float* Wm2     = (const float*)d_in[12];
    const float* bm2     = (const float*)d_in[13];
    const float* Wvm     = (const float*)d_in[14];

    int n_nodes = in_sizes[0] / H;
    int n_edges = in_sizes[4];
    float* out = (float*)d_out;

    // workspace layout
    char* ws = (char*)d_ws;
    size_t off = 0;
    ushort_t* xv  = (ushort_t*)(ws + off); off = align_up(off + (size_t)n_nodes * 768 * 2, 256);
    ushort_t* mid = (ushort_t*)(ws + off); off = align_up(off + (size_t)n_nodes * 512 * 2, 256);
    int* starts = (int*)(ws + off); off = align_up(off + (size_t)n_nodes * 4, 256);
    int* cnt    = (int*)(ws + off); off = align_up(off + (size_t)(n_nodes + 1) * 4, 256);
    int* cursor = cnt + n_nodes;
    int* head   = (int*)(ws + off); off = align_up(off + (size_t)n_nodes * 4, 256);
    int* eord   = (int*)(ws + off); off = align_up(off + (size_t)n_edges * 4, 256);
    float4* edir = (float4*)(ws + off); off = align_up(off + (size_t)n_edges * 16, 256);
    ushort_t* Wi1p = (ushort_t*)(ws + off); off = align_up(off + 16384 * 2, 256);
    ushort_t* Wi2p = (ushort_t*)(ws + off); off = align_up(off + 49152 * 2, 256);
    ushort_t* Wvp  = (ushort_t*)(ws + off); off = align_up(off + 32768 * 2, 256);
    ushort_t* Wm1p = (ushort_t*)(ws + off); off = align_up(off + 32768 * 2, 256);
    ushort_t* Wm2p = (ushort_t*)(ws + off); off = align_up(off + 49152 * 2, 256);
    if (off > ws_size) return;   // ws is ~3.6 GB; always fits

    // zero cnt+cursor, then prep (packs + histogram overlap)
    hipMemsetAsync(cnt, 0, (size_t)(n_nodes + 1) * 4, stream);
    int prep_total = 16384 + 49152 + 32768 + 32768 + 49152 + n_edges;
    int prep_blocks = (prep_total + 255) / 256;
    if (prep_blocks > 2048) prep_blocks = 2048;
    k_prep<<<prep_blocks, 256, 0, stream>>>(
        Wi1, Wi2, Wvm, Wm1, Wm2, Wi1p, Wi2p, Wvp, Wm1p, Wm2p, senders, cnt, n_edges);

    k_alloc<<<(n_nodes + 255) / 256, 256, 0, stream>>>(cnt, starts, head, cursor, n_nodes);
    k_scatter<<<(n_edges + 255) / 256, 256, 0, stream>>>(senders, recv, dir, head, eord, edir, n_edges);

    k1_mfma<<<(n_nodes + 15) / 16, 256, 0, stream>>>(
        s, (const float4*)v, Wi1p, Wi2p, bi1, bi2, xv, n_nodes);

    k2_csr<<<n_nodes, 512, 0, stream>>>(
        (const float4*)s, xv, Wij, starts, cnt, eord, edir, mid, n_nodes);

    k3_mfma<<<(n_nodes + 15) / 16, 256, 0, stream>>>(
        mid, Wvp, Wm1p, Wm2p, bm1, bm2, out, n_nodes);
}

// Round 13
// 454.667 us; speedup vs baseline: 1.0812x; 1.0812x over previous
//
#include <hip/hip_runtime.h>

#define H 128
#define EPSILON 0.7071067811865476f
#define NEPS 1e-8f

typedef short bf16x8 __attribute__((ext_vector_type(8)));
typedef float f32x4 __attribute__((ext_vector_type(4)));
typedef unsigned short ushort_t;

__device__ __forceinline__ float silu_f(float x) {
    return x / (1.0f + __expf(-x));
}
__device__ __forceinline__ unsigned short bfround(float w) {
    unsigned ub = __float_as_uint(w);
    return (unsigned short)((ub + 0x7FFF + ((ub >> 16) & 1)) >> 16);
}
__device__ __forceinline__ float bfu(unsigned short u) { return __uint_as_float(((unsigned)u) << 16); }

// pack one element of a K x N weight into fragment-major bf16
// elem (ks, ct, lane, j) at ((ks*CT+ct)*64+lane)*8+j = W[ks*32+(lane>>4)*8+j][ct*16+(lane&15)]
__device__ __forceinline__ void pack_one(const float* __restrict__ W, int N,
                                         ushort_t* __restrict__ p, int tid) {
    int CT = N >> 4;
    int j = tid & 7;
    int l = (tid >> 3) & 63;
    int rest = tid >> 9;
    int ct = rest % CT;
    int ks = rest / CT;
    int row = ks * 32 + ((l >> 4) << 3) + j;
    int col = ct * 16 + (l & 15);
    p[tid] = bfround(W[(size_t)row * N + col]);
}

// ---------------- K_prep: pack 5 weights + edge histogram (cnt pre-zeroed by memset) ----------------
__global__ void k_prep(const float* __restrict__ Wi1, const float* __restrict__ Wi2,
                       const float* __restrict__ Wvm, const float* __restrict__ Wm1,
                       const float* __restrict__ Wm2,
                       ushort_t* __restrict__ Wi1p, ushort_t* __restrict__ Wi2p,
                       ushort_t* __restrict__ Wvp, ushort_t* __restrict__ Wm1p,
                       ushort_t* __restrict__ Wm2p,
                       const int* __restrict__ senders, int* __restrict__ cnt, int n_edges) {
    int gid = blockIdx.x * blockDim.x + threadIdx.x;
    int stride = gridDim.x * blockDim.x;
    int S1 = 16384;
    int S2 = S1 + 49152;
    int S3 = S2 + 32768;
    int S4 = S3 + 32768;
    int S5 = S4 + 49152;
    int S6 = S5 + n_edges;
    for (int i = gid; i < S6; i += stride) {
        if (i < S1)      pack_one(Wi1, 128, Wi1p, i);
        else if (i < S2) pack_one(Wi2, 384, Wi2p, i - S1);
        else if (i < S3) pack_one(Wvm, 256, Wvp,  i - S2);
        else if (i < S4) pack_one(Wm1, 128, Wm1p, i - S3);
        else if (i < S5) pack_one(Wm2, 384, Wm2p, i - S4);
        else             atomicAdd(&cnt[senders[i - S5]], 1);
    }
}

// ---------------- K1 (MFMA): x = silu(s@Wi1+bi1)@Wi2+bi2 -> xv[0:384]; also v -> xv[384:768] ----------------
__global__ __launch_bounds__(256, 6) void k1_mfma(
        const float* __restrict__ s, const float4* __restrict__ v4,
        const ushort_t* __restrict__ W1p, const ushort_t* __restrict__ W2p,
        const float* __restrict__ bi1, const float* __restrict__ bi2,
        ushort_t* __restrict__ xv, int n_nodes) {
    __shared__ ushort_t Ab[16 * 136];
    __shared__ ushort_t Hb[16 * 136];
    int t = threadIdx.x;
    int node0 = blockIdx.x * 16;
    int wv = t >> 6, lane = t & 63;
    int g = lane >> 4, cl = lane & 15;

    #pragma unroll
    for (int i = 0; i < 8; ++i) {
        int flat = t + i * 256;
        int n = flat >> 7, k = flat & 127;
        int node = node0 + n; if (node >= n_nodes) node = n_nodes - 1;
        Ab[n * 136 + k] = bfround(s[(size_t)node * 128 + k]);
    }
    __syncthreads();

    f32x4 acc1[2] = {};
    #pragma unroll
    for (int ks = 0; ks < 4; ++ks) {
        bf16x8 ah = *(const bf16x8*)&Ab[cl * 136 + ks * 32 + g * 8];
        #pragma unroll
        for (int c = 0; c < 2; ++c) {
            int ct = wv * 2 + c;
            bf16x8 bh = *(const bf16x8*)&W1p[((size_t)(ks * 8 + ct) * 64 + lane) * 8];
            acc1[c] = __builtin_amdgcn_mfma_f32_16x16x32_bf16(ah, bh, acc1[c], 0, 0, 0);
        }
    }
    #pragma unroll
    for (int c = 0; c < 2; ++c) {
        int col = (wv * 2 + c) * 16 + cl;
        float bias = bi1[col];
        #pragma unroll
        for (int r = 0; r < 4; ++r) {
            int row = g * 4 + r;
            Hb[row * 136 + col] = bfround(silu_f(acc1[c][r] + bias));
        }
    }
    __syncthreads();

    f32x4 acc2[6] = {};
    #pragma unroll
    for (int ks = 0; ks < 4; ++ks) {
        bf16x8 ah = *(const bf16x8*)&Hb[cl * 136 + ks * 32 + g * 8];
        #pragma unroll
        for (int c = 0; c < 6; ++c) {
            int ct = wv * 6 + c;
            bf16x8 bh = *(const bf16x8*)&W2p[((size_t)(ks * 24 + ct) * 64 + lane) * 8];
            acc2[c] = __builtin_amdgcn_mfma_f32_16x16x32_bf16(ah, bh, acc2[c], 0, 0, 0);
        }
    }
    #pragma unroll
    for (int c = 0; c < 6; ++c) {
        int col = (wv * 6 + c) * 16 + cl;
        float bias = bi2[col];
        #pragma unroll
        for (int r = 0; r < 4; ++r) {
            int node = node0 + g * 4 + r;
            if (node < n_nodes) xv[(size_t)node * 768 + col] = bfround(acc2[c][r] + bias);
        }
    }

    // convert these 16 nodes' v rows -> xv[384:768]
    #pragma unroll
    for (int i = 0; i < 6; ++i) {
        int flat = t + i * 256;               // 0..1535 = 16 nodes * 96 float4
        int n = flat / 96, part = flat - n * 96;
        int node = node0 + n;
        if (node < n_nodes) {
            float4 f = v4[(size_t)node * 96 + part];
            ushort4 u;
            u.x = bfround(f.x); u.y = bfround(f.y); u.z = bfround(f.z); u.w = bfround(f.w);
            *(ushort4*)&xv[(size_t)node * 768 + 384 + 4 * part] = u;
        }
    }
}

// ---------------- CSR build ----------------
__global__ void k_alloc(const int* __restrict__ cnt, int* __restrict__ starts,
                        int* __restrict__ head, int* __restrict__ cursor, int n) {
    int i = blockIdx.x * blockDim.x + threadIdx.x;
    int lane = threadIdx.x & 63;
    int c = (i < n) ? cnt[i] : 0;
    int pref = c;
    #pragma unroll
    for (int off = 1; off < 64; off <<= 1) {
        int up = __shfl_up(pref, off, 64);
        if (lane >= off) pref += up;
    }
    int total = __shfl(pref, 63, 64);
    int base = 0;
    if (lane == 63) base = atomicAdd(cursor, total);
    base = __shfl(base, 63, 64);
    if (i < n) { int p = base + pref - c; starts[i] = p; head[i] = p; }
}

__global__ void k_scatter(const int* __restrict__ senders, const int* __restrict__ receivers,
                          const float* __restrict__ dir, int* __restrict__ head,
                          int* __restrict__ eord, float4* __restrict__ edir, int n_edges) {
    int e = blockIdx.x * blockDim.x + threadIdx.x;
    if (e < n_edges) {
        int p = atomicAdd(&head[senders[e]], 1);
        eord[p] = e;
        float4 ed;
        ed.x = dir[3 * (size_t)e + 0];
        ed.y = dir[3 * (size_t)e + 1];
        ed.z = dir[3 * (size_t)e + 2];
        ed.w = __int_as_float(receivers[e]);
        edir[p] = ed;
    }
}

// ---------------- K2 (CSR): per-node gather-accumulate -> bf16 mid (round-9 best config) ----------------
__global__ __launch_bounds__(256) void k2_csr(
        const float4* __restrict__ s4, const ushort_t* __restrict__ xv,
        const float* __restrict__ wf, const int* __restrict__ starts,
        const int* __restrict__ cnt, const int* __restrict__ eord,
        const float4* __restrict__ edir, ushort_t* __restrict__ mid, int n_nodes) {
    __shared__ float4 red[8][128];
    int node = blockIdx.x;
    int t = threadIdx.x;
    int slot = t >> 5, lane = t & 31;
    int beg = starts[node], num = cnt[node];
    float4 ds  = {0.f, 0.f, 0.f, 0.f};
    float4 dv0 = {0.f, 0.f, 0.f, 0.f};
    float4 dv1 = {0.f, 0.f, 0.f, 0.f};
    float4 dv2 = {0.f, 0.f, 0.f, 0.f};
    for (int q = slot; q < num; q += 8) {
        int e = eord[beg + q];
        float4 ed = edir[beg + q];
        int r = __float_as_int(ed.w);
        const f32x4*    we  = (const f32x4*)(wf + (size_t)e * 384);
        const ushort_t* xvr = xv + (size_t)r * 768;
        // non-temporal: Wij is a 922 MB read-once stream; don't evict xv from L2/L3
        f32x4 wa = __builtin_nontemporal_load(we + lane);
        f32x4 wb = __builtin_nontemporal_load(we + 32 + lane);
        f32x4 wc = __builtin_nontemporal_load(we + 64 + lane);
        ushort4 xa = *(const ushort4*)&xvr[4 * lane];
        ushort4 xb = *(const ushort4*)&xvr[128 + 4 * lane];
        ushort4 xc = *(const ushort4*)&xvr[256 + 4 * lane];
        ushort4 va = *(const ushort4*)&xvr[384 + 4 * lane];
        ushort4 vb = *(const ushort4*)&xvr[512 + 4 * lane];
        ushort4 vc = *(const ushort4*)&xvr[640 + 4 * lane];
        float bx = wb[0] * bfu(xb.x), by = wb[1] * bfu(xb.y), bz = wb[2] * bfu(xb.z), bw = wb[3] * bfu(xb.w);
        float cx = wc[0] * bfu(xc.x), cy = wc[1] * bfu(xc.y), cz = wc[2] * bfu(xc.z), cw = wc[3] * bfu(xc.w);
        ds.x += wa[0] * bfu(xa.x); ds.y += wa[1] * bfu(xa.y);
        ds.z += wa[2] * bfu(xa.z); ds.w += wa[3] * bfu(xa.w);
        dv0.x += bx * ed.x + cx * bfu(va.x); dv0.y += by * ed.x + cy * bfu(va.y);
        dv0.z += bz * ed.x + cz * bfu(va.z); dv0.w += bw * ed.x + cw * bfu(va.w);
        dv1.x += bx * ed.y + cx * bfu(vb.x); dv1.y += by * ed.y + cy * bfu(vb.y);
        dv1.z += bz * ed.y + cz * bfu(vb.z); dv1.w += bw * ed.y + cw * bfu(vb.w);
        dv2.x += bx * ed.z + cx * bfu(vc.x); dv2.y += by * ed.z + cy * bfu(vc.y);
        dv2.z += bz * ed.z + cz * bfu(vc.z); dv2.w += bw * ed.z + cw * bfu(vc.w);
    }

    red[slot][lane]      = ds;
    red[slot][32 + lane] = dv0;
    red[slot][64 + lane] = dv1;
    red[slot][96 + lane] = dv2;
    __syncthreads();
    if (t < 128) {
        float4 acc = red[0][t];
        #pragma unroll
        for (int q2 = 1; q2 < 8; ++q2) {
            float4 r2 = red[q2][t];
            acc.x += r2.x; acc.y += r2.y; acc.z += r2.z; acc.w += r2.w;
        }
        int which = t >> 5, hh = t & 31;
        float4 base;
        if (which == 0) {
            base = s4[(size_t)node * 32 + hh];
        } else {
            ushort4 u = *(const ushort4*)&xv[(size_t)node * 768 + 384 + (size_t)(which - 1) * 128 + 4 * hh];
            base.x = bfu(u.x); base.y = bfu(u.y); base.z = bfu(u.z); base.w = bfu(u.w);
        }
        ushort4 o;
        o.x = bfround((base.x + acc.x) * EPSILON);
        o.y = bfround((base.y + acc.y) * EPSILON);
        o.z = bfround((base.z + acc.z) * EPSILON);
        o.w = bfround((base.w + acc.w) * EPSILON);
        *(ushort4*)&mid[(size_t)node * 512 + 4 * t] = o;
    }
}

// ---------------- K3 (MFMA): fused update; reads bf16 mid, writes fp32 out ----------------
__global__ __launch_bounds__(256, 3) void k3_mfma(
        const ushort_t* __restrict__ mid,
        const ushort_t* __restrict__ Wvp, const ushort_t* __restrict__ W1p,
        const ushort_t* __restrict__ W2p,
        const float* __restrict__ bm1, const float* __restrict__ bm2,
        float* __restrict__ out, int n_nodes) {
    __shared__ __align__(16) char pool[51968];
    ushort_t* Ab  = (ushort_t*)pool;
    ushort_t* vlb = (ushort_t*)(pool + 13056);
    ushort_t* vrc = (ushort_t*)(pool + 26112);
    ushort_t* Tb  = (ushort_t*)(pool + 39168);
    ushort_t* Hb  = (ushort_t*)(pool + 47616);
    float* C3 = (float*)(pool + 26112);   // [16][400]

    int t = threadIdx.x;
    int node0 = blockIdx.x * 16;
    int wv = t >> 6, lane = t & 63;
    int g = lane >> 4, cl = lane & 15;

    float smid_reg[8], dot_reg[8];

    #pragma unroll
    for (int i = 0; i < 6; ++i) {
        int flat4 = t + i * 256;
        int row = flat4 >> 5, k4 = flat4 & 31;
        int n = row / 3, d = row - n * 3;
        int node = node0 + n; if (node >= n_nodes) node = n_nodes - 1;
        ushort4 u = *(const ushort4*)&mid[(size_t)node * 512 + (size_t)(1 + d) * 128 + 4 * k4];
        *(ushort4*)&Ab[row * 136 + 4 * k4] = u;
    }
    #pragma unroll
    for (int i = 0; i < 8; ++i) {
        int flat = t + i * 256;
        int n = flat >> 7, k = flat & 127;
        int node = node0 + n; if (node >= n_nodes) node = n_nodes - 1;
        smid_reg[i] = bfu(mid[(size_t)node * 512 + k]);
    }
    __syncthreads();

    // GEMM1: (48x128)@(128x256) -> v_l | v_r
    #pragma unroll
    for (int rt = 0; rt < 3; ++rt) {
        bf16x8 ah[4];
        #pragma unroll
        for (int ks = 0; ks < 4; ++ks)
            ah[ks] = *(const bf16x8*)&Ab[(rt * 16 + cl) * 136 + ks * 32 + g * 8];
        f32x4 acc[4] = {};
        #pragma unroll
        for (int ks = 0; ks < 4; ++ks) {
            #pragma unroll
            for (int c = 0; c < 4; ++c) {
                int ct = wv * 4 + c;
                bf16x8 bh = *(const bf16x8*)&Wvp[((size_t)(ks * 16 + ct) * 64 + lane) * 8];
                acc[c] = __builtin_amdgcn_mfma_f32_16x16x32_bf16(ah[ks], bh, acc[c], 0, 0, 0);
            }
        }
        #pragma unroll
        for (int c = 0; c < 4; ++c) {
            int col = (wv * 4 + c) * 16 + cl;
            ushort_t* dst = (col < 128) ? vlb : vrc;
            int cc = col & 127;
            #pragma unroll
            for (int r = 0; r < 4; ++r)
                dst[(rt * 16 + g * 4 + r) * 136 + cc] = bfround(acc[c][r]);
        }
    }
    __syncthreads();

    // phase 2: v_norm, dot -> regs; build ts
    #pragma unroll
    for (int i = 0; i < 8; ++i) {
        int flat = t + i * 256;
        int n = flat >> 7, h = flat & 127;
        float r0 = bfu(vrc[(3 * n + 0) * 136 + h]);
        float r1 = bfu(vrc[(3 * n + 1) * 136 + h]);
        float r2 = bfu(vrc[(3 * n + 2) * 136 + h]);
        float l0 = bfu(vlb[(3 * n + 0) * 136 + h]);
        float l1 = bfu(vlb[(3 * n + 1) * 136 + h]);
        float l2 = bfu(vlb[(3 * n + 2) * 136 + h]);
        float nrm = sqrtf(r0 * r0 + r1 * r1 + r2 * r2 + NEPS);
        dot_reg[i] = r0 * l0 + r1 * l1 + r2 * l2;
        Tb[n * 264 + 128 + h] = bfround(nrm);
        Tb[n * 264 + h] = bfround(smid_reg[i]);
    }
    __syncthreads();

    // GEMM2: (16x256)@(256x128) + bm1 -> silu -> h1
    f32x4 acc2[2] = {};
    #pragma unroll
    for (int ks = 0; ks < 8; ++ks) {
        bf16x8 ah = *(const bf16x8*)&Tb[cl * 264 + ks * 32 + g * 8];
        #pragma unroll
        for (int c = 0; c < 2; ++c) {
            int ct = wv * 2 + c;
            bf16x8 bh = *(const bf16x8*)&W1p[((size_t)(ks * 8 + ct) * 64 + lane) * 8];
            acc2[c] = __builtin_amdgcn_mfma_f32_16x16x32_bf16(ah, bh, acc2[c], 0, 0, 0);
        }
    }
    #pragma unroll
    for (int c = 0; c < 2; ++c) {
        int col = (wv * 2 + c) * 16 + cl;
        float bias = bm1[col];
        #pragma unroll
        for (int r = 0; r < 4; ++r) {
            int row = g * 4 + r;
            Hb[row * 136 + col] = bfround(silu_f(acc2[c][r] + bias));
        }
    }
    __syncthreads();

    // GEMM3: (16x128)@(128x384) + bm2 -> C3 (overlay)
    f32x4 acc3[6] = {};
    #pragma unroll
    for (int ks = 0; ks < 4; ++ks) {
        bf16x8 ah = *(const bf16x8*)&Hb[cl * 136 + ks * 32 + g * 8];
        #pragma unroll
        for (int c = 0; c < 6; ++c) {
            int ct = wv * 6 + c;
            bf16x8 bh = *(const bf16x8*)&W2p[((size_t)(ks * 24 + ct) * 64 + lane) * 8];
            acc3[c] = __builtin_amdgcn_mfma_f32_16x16x32_bf16(ah, bh, acc3[c], 0, 0, 0);
        }
    }
    __syncthreads();
    #pragma unroll
    for (int c = 0; c < 6; ++c) {
        int col = (wv * 6 + c) * 16 + cl;
        float bias = bm2[col];
        #pragma unroll
        for (int r = 0; r < 4; ++r)
            C3[(g * 4 + r) * 400 + col] = acc3[c][r] + bias;
    }
    __syncthreads();

    // final combine (non-temporal stores: out is write-once)
    #pragma unroll
    for (int i = 0; i < 8; ++i) {
        int flat = t + i * 256;
        int n = flat >> 7, h = flat & 127;
        int node = node0 + n;
        if (node >= n_nodes) continue;
        float ds_u = C3[n * 400 + h];
        float dv_u = C3[n * 400 + 128 + h];
        float dsv  = C3[n * 400 + 256 + h] * dot_reg[i];
        __builtin_nontemporal_store((smid_reg[i] + ds_u + dsv) * EPSILON,
                                    &out[(size_t)node * 512 + h]);
        #pragma unroll
        for (int d = 0; d < 3; ++d) {
            int row = 3 * n + d;
            float vmid = bfu(Ab[row * 136 + h]);
            float vl_v = bfu(vlb[row * 136 + h]);
            __builtin_nontemporal_store((vmid + vl_v * dv_u) * EPSILON,
                                        &out[(size_t)node * 512 + 128 + d * 128 + h]);
        }
    }
}

static inline size_t align_up(size_t x, size_t a) { return (x + a - 1) / a * a; }

extern "C" void kernel_launch(void* const* d_in, const int* in_sizes, int n_in,
                              void* d_out, int out_size, void* d_ws, size_t ws_size,
                              hipStream_t stream) {
    const float* s       = (const float*)d_in[0];
    const float* v       = (const float*)d_in[1];
    const float* dir     = (const float*)d_in[2];
    const float* Wij     = (const float*)d_in[3];
    const int*   senders = (const int*)d_in[4];
    const int*   recv    = (const int*)d_in[5];
    const float* Wi1     = (const float*)d_in[6];
    const float* bi1     = (const float*)d_in[7];
    const float* Wi2     = (const float*)d_in[8];
    const float* bi2     = (const float*)d_in[9];
    const float* Wm1     = (const float*)d_in[10];
    const float* bm1     = (const float*)d_in[11];
    const float* Wm2     = (const float*)d_in[12];
    const float* bm2     = (const float*)d_in[13];
    const float* Wvm     = (const float*)d_in[14];

    int n_nodes = in_sizes[0] / H;
    int n_edges = in_sizes[4];
    float* out = (float*)d_out;

    // workspace layout
    char* ws = (char*)d_ws;
    size_t off = 0;
    ushort_t* xv  = (ushort_t*)(ws + off); off = align_up(off + (size_t)n_nodes * 768 * 2, 256);
    ushort_t* mid = (ushort_t*)(ws + off); off = align_up(off + (size_t)n_nodes * 512 * 2, 256);
    int* starts = (int*)(ws + off); off = align_up(off + (size_t)n_nodes * 4, 256);
    int* cnt    = (int*)(ws + off); off = align_up(off + (size_t)(n_nodes + 1) * 4, 256);
    int* cursor = cnt + n_nodes;
    int* head   = (int*)(ws + off); off = align_up(off + (size_t)n_nodes * 4, 256);
    int* eord   = (int*)(ws + off); off = align_up(off + (size_t)n_edges * 4, 256);
    float4* edir = (float4*)(ws + off); off = align_up(off + (size_t)n_edges * 16, 256);
    ushort_t* Wi1p = (ushort_t*)(ws + off); off = align_up(off + 16384 * 2, 256);
    ushort_t* Wi2p = (ushort_t*)(ws + off); off = align_up(off + 49152 * 2, 256);
    ushort_t* Wvp  = (ushort_t*)(ws + off); off = align_up(off + 32768 * 2, 256);
    ushort_t* Wm1p = (ushort_t*)(ws + off); off = align_up(off + 32768 * 2, 256);
    ushort_t* Wm2p = (ushort_t*)(ws + off); off = align_up(off + 49152 * 2, 256);
    if (off > ws_size) return;   // ws is ~3.6 GB; always fits

    // zero cnt+cursor, then prep (packs + histogram overlap)
    hipMemsetAsync(cnt, 0, (size_t)(n_nodes + 1) * 4, stream);
    int prep_total = 16384 + 49152 + 32768 + 32768 + 49152 + n_edges;
    int prep_blocks = (prep_total + 255) / 256;
    if (prep_blocks > 2048) prep_blocks = 2048;
    k_prep<<<prep_blocks, 256, 0, stream>>>(
        Wi1, Wi2, Wvm, Wm1, Wm2, Wi1p, Wi2p, Wvp, Wm1p, Wm2p, senders, cnt, n_edges);

    k_alloc<<<(n_nodes + 255) / 256, 256, 0, stream>>>(cnt, starts, head, cursor, n_nodes);
    k_scatter<<<(n_edges + 255) / 256, 256, 0, stream>>>(senders, recv, dir, head, eord, edir, n_edges);

    k1_mfma<<<(n_nodes + 15) / 16, 256, 0, stream>>>(
        s, (const float4*)v, Wi1p, Wi2p, bi1, bi2, xv, n_nodes);

    k2_csr<<<n_nodes, 256, 0, stream>>>(
        (const float4*)s, xv, Wij, starts, cnt, eord, edir, mid, n_nodes);

    k3_mfma<<<(n_nodes + 15) / 16, 256, 0, stream>>>(
        mid, Wvp, Wm1p, Wm2p, bm1, bm2, out, n_nodes);
}